// Round 2
// baseline (226.049 us; speedup 1.0000x reference)
//
#include <hip/hip_runtime.h>

#define TOKS 12544

using bf16x8 = __attribute__((ext_vector_type(8))) short;
using f32x4  = __attribute__((ext_vector_type(4))) float;
typedef unsigned short u16;

__device__ __forceinline__ u16 f2b(float f){
  unsigned int i=__float_as_uint(f);
  return (u16)((i + 0x7FFFu + ((i>>16)&1u))>>16);
}
__device__ __forceinline__ float b2f(u16 u){
  union{unsigned int i; float f;}v; v.i=((unsigned int)u)<<16; return v.f;
}
__device__ __forceinline__ void async16(const void* g, void* l){
  __builtin_amdgcn_global_load_lds((__attribute__((address_space(1))) void*)(g),
                                   (__attribute__((address_space(3))) void*)(l), 16, 0, 0);
}

// ---------- prep: fp32 weights -> bf16, transposed to [N][K] ----------
__global__ void prep_kernel(const float* __restrict__ wqkv, const float* __restrict__ wproj,
                            const float* __restrict__ wfc1, const float* __restrict__ wfc2,
                            u16* __restrict__ tqkv, u16* __restrict__ tproj,
                            u16* __restrict__ tfc1, u16* __restrict__ tfc2)
{
  int idx = blockIdx.x*256 + threadIdx.x;
  if (idx < 49152){ int n=idx>>7, k=idx&127; tqkv[idx]=f2b(wqkv[k*384+n]); }
  else if (idx < 65536){ int t=idx-49152; int n=t>>7, k=t&127; tproj[t]=f2b(wproj[k*128+n]); }
  else if (idx < 131072){ int t=idx-65536; int n=t>>7, k=t&127; tfc1[t]=f2b(wfc1[k*512+n]); }
  else if (idx < 196608){ int t=idx-131072; int n=t>>9, k=t&511; tfc2[t]=f2b(wfc2[k*128+n]); }
}

// ---------- layernorm: wave per token, 128 channels, fp32 in -> bf16 out ----------
__global__ __launch_bounds__(256)
void ln_kernel(const float* __restrict__ xin, const float* __restrict__ w,
               const float* __restrict__ bia, u16* __restrict__ out)
{
  int lane = threadIdx.x & 63;
  int token = blockIdx.x*4 + (threadIdx.x>>6);
  float2 t = ((const float2*)xin)[token*64 + lane];
  float x0=t.x, x1=t.y;
  float s=x0+x1, q=x0*x0+x1*x1;
  #pragma unroll
  for (int off=32; off; off>>=1){ s+=__shfl_xor(s,off); q+=__shfl_xor(q,off); }
  float m = s*0.0078125f;
  float r = rsqrtf(q*0.0078125f - m*m + 1e-5f);
  int c = lane*2;
  ushort2 o;
  o.x = f2b((x0-m)*r*w[c]   + bia[c]);
  o.y = f2b((x1-m)*r*w[c+1] + bia[c+1]);
  ((ushort2*)out)[token*64+lane]=o;
}

// ---------- MFMA GEMM: C[M,N] = A[M,K](bf16) * Bt[N,K](bf16)^T + bias(fp32) ----------
#define M_QKV 0
#define M_PROJ 1
#define M_FC1 2
#define M_FC2 3

template<int MODE>
__global__ __launch_bounds__(256)
void gemm_kernel(const u16* __restrict__ A, const u16* __restrict__ Bt,
                 const float* __restrict__ bias, int K,
                 const float* __restrict__ aux,
                 float* __restrict__ fo0, float* __restrict__ fo1, float* __restrict__ fo2,
                 u16* __restrict__ bo0)
{
  __shared__ __align__(16) u16 lA[128*32];
  __shared__ __align__(16) u16 lB[128*32];
  const int tid=threadIdx.x;
  const int lane=tid&63, wid=tid>>6;
  const int quad=lane>>4, lrow=lane&15;
  const int m0=blockIdx.x*128, n0=blockIdx.y*128;
  const int wm=(wid&1)*64, wn=(wid>>1)*64;
  f32x4 acc[4][4] = {};

  const int c0=tid, c1=tid+256;
  const int rA0=c0>>2, hA0=c0&3, rA1=c1>>2, hA1=c1&3;

  for (int k0=0;k0<K;k0+=32){
    async16(A  + (size_t)(m0+rA0)*K + k0 + hA0*8, (char*)lA + c0*16);
    async16(A  + (size_t)(m0+rA1)*K + k0 + hA1*8, (char*)lA + c1*16);
    async16(Bt + (size_t)(n0+rA0)*K + k0 + hA0*8, (char*)lB + c0*16);
    async16(Bt + (size_t)(n0+rA1)*K + k0 + hA1*8, (char*)lB + c1*16);
    __syncthreads();
    bf16x8 af[4], bfr[4];
    #pragma unroll
    for (int i=0;i<4;i++){
      af[i]  = ((const bf16x8*)lA)[(wm+i*16+lrow)*4 + quad];
      bfr[i] = ((const bf16x8*)lB)[(wn+i*16+lrow)*4 + quad];
    }
    #pragma unroll
    for (int i=0;i<4;i++){
      #pragma unroll
      for (int j=0;j<4;j++){
        acc[i][j] = __builtin_amdgcn_mfma_f32_16x16x32_bf16(af[i], bfr[j], acc[i][j], 0,0,0);
      }
    }
    __syncthreads();
  }

  const float scale = 0.17677669529663687f;
  #pragma unroll
  for (int i=0;i<4;i++){
    #pragma unroll
    for (int j=0;j<4;j++){
      #pragma unroll
      for (int r=0;r<4;r++){
        int row = m0 + wm + i*16 + quad*4 + r;   // token
        int col = n0 + wn + j*16 + lrow;         // output channel
        float val = acc[i][j][r] + bias[col];
        if (MODE==M_QKV){
          int which = col>>7, h=(col>>5)&3, d=col&31;
          float* dst = (which==0)? fo0 : ((which==1)? fo1 : fo2);
          if (which==0) val *= scale;
          dst[((size_t)h*TOKS + row)*32 + d] = val;
        } else if (MODE==M_PROJ){
          val += aux[(size_t)row*128+col];             // + x residual (fp32)
          fo0[(size_t)row*128+col]=val;
        } else if (MODE==M_FC1){
          float g = 0.5f*val*(1.0f+erff(val*0.70710678118654752f));
          bo0[(size_t)row*512+col]=f2b(g);
        } else {
          val += aux[(size_t)row*128+col];             // + x1 residual (fp32)
          fo0[(size_t)row*128+col]=val;                // fp32 final output
        }
      }
    }
  }
}

// ---------- neighborhood attention: one thread per (pixel, head) ----------
__global__ __launch_bounds__(64)
void attn_kernel(const float* __restrict__ qb, const float* __restrict__ kb,
                 const float* __restrict__ vb, const float* __restrict__ rpb,
                 u16* __restrict__ aout)
{
  int lane = threadIdx.x;
  int tile = blockIdx.x;           // 49 tiles of 8x8
  int b = blockIdx.y>>2, h = blockIdx.y&3;
  int py = (tile/7)*8 + (lane>>3);
  int px = (tile%7)*8 + (lane&7);
  int tok = b*3136 + py*56 + px;

  float4 qv[8];
  const float4* qr = (const float4*)(qb + ((size_t)h*TOKS + tok)*32);
  #pragma unroll
  for (int i=0;i<8;i++) qv[i]=qr[i];

  float sc[49];
  #pragma unroll
  for (int ky=0;ky<7;ky++){
    int gy = py+ky-3;
    #pragma unroll
    for (int kx=0;kx<7;kx++){
      int gx = px+kx-3;
      int n = ky*7+kx;
      float s=0.f;
      if (gy>=0 && gy<56 && gx>=0 && gx<56){
        const float4* kr=(const float4*)(kb + ((size_t)h*TOKS + b*3136 + gy*56 + gx)*32);
        #pragma unroll
        for (int i=0;i<8;i++){
          float4 kk=kr[i];
          s += qv[i].x*kk.x + qv[i].y*kk.y + qv[i].z*kk.z + qv[i].w*kk.w;
        }
      }
      sc[n] = s + rpb[h*49+n];   // zero-padded OOB: score = 0 + rpb (matches ref)
    }
  }
  float m=-1e30f;
  #pragma unroll
  for (int n=0;n<49;n++) m = fmaxf(m, sc[n]);
  float l=0.f;
  #pragma unroll
  for (int n=0;n<49;n++){ sc[n]=__expf(sc[n]-m); l+=sc[n]; }
  float inv = 1.f/l;

  float4 o[8]={};
  #pragma unroll
  for (int ky=0;ky<7;ky++){
    int gy = py+ky-3;
    #pragma unroll
    for (int kx=0;kx<7;kx++){
      int gx = px+kx-3;
      int n = ky*7+kx;
      if (gy>=0 && gy<56 && gx>=0 && gx<56){
        const float4* vr=(const float4*)(vb + ((size_t)h*TOKS + b*3136 + gy*56 + gx)*32);
        float p = sc[n];
        #pragma unroll
        for (int i=0;i<8;i++){
          float4 vv=vr[i];
          o[i].x += p*vv.x; o[i].y += p*vv.y; o[i].z += p*vv.z; o[i].w += p*vv.w;
        }
      }
    }
  }
  u16* orow = aout + (size_t)tok*128 + h*32;
  #pragma unroll
  for (int i=0;i<8;i++){
    ushort4 st;
    st.x=f2b(o[i].x*inv); st.y=f2b(o[i].y*inv);
    st.z=f2b(o[i].z*inv); st.w=f2b(o[i].w*inv);
    ((ushort4*)orow)[i]=st;
  }
}

extern "C" void kernel_launch(void* const* d_in, const int* in_sizes, int n_in,
                              void* d_out, int out_size, void* d_ws, size_t ws_size,
                              hipStream_t stream)
{
  const float* x     =(const float*)d_in[0];
  const float* ln1w  =(const float*)d_in[1];
  const float* ln1b  =(const float*)d_in[2];
  const float* wqkv  =(const float*)d_in[3];
  const float* bqkv  =(const float*)d_in[4];
  const float* rpb   =(const float*)d_in[5];
  const float* wproj =(const float*)d_in[6];
  const float* bproj =(const float*)d_in[7];
  const float* ln2w  =(const float*)d_in[8];
  const float* ln2b  =(const float*)d_in[9];
  const float* wfc1  =(const float*)d_in[10];
  const float* bfc1  =(const float*)d_in[11];
  const float* wfc2  =(const float*)d_in[12];
  const float* bfc2  =(const float*)d_in[13];

  char* ws=(char*)d_ws;
  size_t o=0;
  u16* tqkv =(u16*)(ws+o); o+=98304;
  u16* tproj=(u16*)(ws+o); o+=32768;
  u16* tfc1 =(u16*)(ws+o); o+=131072;
  u16* tfc2 =(u16*)(ws+o); o+=131072;
  u16* xn   =(u16*)(ws+o); o+=3211264;   // LN1 out, bf16 [12544][128]
  u16* aout =(u16*)(ws+o); o+=3211264;   // attn out, bf16 [12544][128]
  u16* xn2  =(u16*)(ws+o); o+=3211264;   // LN2 out, bf16
  u16* hbuf =(u16*)(ws+o); o+=12845056;  // gelu(fc1), bf16 [12544][512]
  float* qb =(float*)(ws+o); o+=6422528; // q scaled fp32 [4][12544][32]
  float* kb =(float*)(ws+o); o+=6422528;
  float* vb =(float*)(ws+o); o+=6422528;
  float* x1 =(float*)(ws+o); o+=6422528; // x + proj, fp32 [12544][128]

  prep_kernel<<<768,256,0,stream>>>(wqkv,wproj,wfc1,wfc2,tqkv,tproj,tfc1,tfc2);
  ln_kernel<<<3136,256,0,stream>>>(x,ln1w,ln1b,xn);
  gemm_kernel<M_QKV><<<dim3(98,3),256,0,stream>>>(xn,tqkv,bqkv,128,nullptr,qb,kb,vb,nullptr);
  attn_kernel<<<dim3(49,16),64,0,stream>>>(qb,kb,vb,rpb,aout);
  gemm_kernel<M_PROJ><<<dim3(98,1),256,0,stream>>>(aout,tproj,bproj,128,x,x1,nullptr,nullptr,nullptr);
  ln_kernel<<<3136,256,0,stream>>>(x1,ln2w,ln2b,xn2);
  gemm_kernel<M_FC1><<<dim3(98,4),256,0,stream>>>(xn2,tfc1,bfc1,128,nullptr,nullptr,nullptr,nullptr,hbuf);
  gemm_kernel<M_FC2><<<dim3(98,1),256,0,stream>>>(hbuf,tfc2,bfc2,512,x1,(float*)d_out,nullptr,nullptr,nullptr);
}

// Round 3
// 191.726 us; speedup vs baseline: 1.1790x; 1.1790x over previous
//
#include <hip/hip_runtime.h>

#define TOKS 12544

using bf16x8 = __attribute__((ext_vector_type(8))) short;
using f32x4  = __attribute__((ext_vector_type(4))) float;
typedef unsigned short u16;
typedef __attribute__((ext_vector_type(8))) unsigned short u16x8;

__device__ __forceinline__ u16 f2b(float f){
  unsigned int i=__float_as_uint(f);
  return (u16)((i + 0x7FFFu + ((i>>16)&1u))>>16);
}
__device__ __forceinline__ float b2f(u16 u){
  union{unsigned int i; float f;}v; v.i=((unsigned int)u)<<16; return v.f;
}
__device__ __forceinline__ void async16(const void* g, void* l){
  __builtin_amdgcn_global_load_lds((__attribute__((address_space(1))) void*)(g),
                                   (__attribute__((address_space(3))) void*)(l), 16, 0, 0);
}

// ---------- prep: fp32 weights -> bf16, transposed to [N][K] ----------
__global__ void prep_kernel(const float* __restrict__ wqkv, const float* __restrict__ wproj,
                            const float* __restrict__ wfc1, const float* __restrict__ wfc2,
                            u16* __restrict__ tqkv, u16* __restrict__ tproj,
                            u16* __restrict__ tfc1, u16* __restrict__ tfc2)
{
  int idx = blockIdx.x*256 + threadIdx.x;
  if (idx < 49152){ int n=idx>>7, k=idx&127; tqkv[idx]=f2b(wqkv[k*384+n]); }
  else if (idx < 65536){ int t=idx-49152; int n=t>>7, k=t&127; tproj[t]=f2b(wproj[k*128+n]); }
  else if (idx < 131072){ int t=idx-65536; int n=t>>7, k=t&127; tfc1[t]=f2b(wfc1[k*512+n]); }
  else if (idx < 196608){ int t=idx-131072; int n=t>>9, k=t&511; tfc2[t]=f2b(wfc2[k*128+n]); }
}

// ---------- layernorm (LN1): wave per token, fp32 in -> bf16 out ----------
__global__ __launch_bounds__(256)
void ln_kernel(const float* __restrict__ xin, const float* __restrict__ w,
               const float* __restrict__ bia, u16* __restrict__ out)
{
  int lane = threadIdx.x & 63;
  int token = blockIdx.x*4 + (threadIdx.x>>6);
  float2 t = ((const float2*)xin)[token*64 + lane];
  float x0=t.x, x1=t.y;
  float s=x0+x1, q=x0*x0+x1*x1;
  #pragma unroll
  for (int off=32; off; off>>=1){ s+=__shfl_xor(s,off); q+=__shfl_xor(q,off); }
  float m = s*0.0078125f;
  float r = rsqrtf(q*0.0078125f - m*m + 1e-5f);
  int c = lane*2;
  ushort2 o;
  o.x = f2b((x0-m)*r*w[c]   + bia[c]);
  o.y = f2b((x1-m)*r*w[c+1] + bia[c+1]);
  ((ushort2*)out)[token*64+lane]=o;
}

// ---------- MFMA GEMM: 64x128 tile; C = A[M,K]*Bt[N,K]^T + bias; fused epilogues ----------
#define M_QKV 0
#define M_PROJ 1
#define M_FC1 2
#define M_FC2 3

// PROJ LN scratch layout: dword idx = row*148 + (col>>5)*36 + (col&31)
#define LNROW 148
#define LNGRP 36

template<int MODE>
__global__ __launch_bounds__(256)
void gemm_kernel(const u16* __restrict__ A, const u16* __restrict__ Bt,
                 const float* __restrict__ bias, int K,
                 const float* __restrict__ aux,     // PROJ: x (fp32); FC2: x1 (fp32)
                 const float* __restrict__ lnw, const float* __restrict__ lnb,
                 float* __restrict__ fout,          // PROJ: x1; FC2: d_out
                 u16* __restrict__ bout0,           // QKV: qb; PROJ: xn2; FC1: hbuf
                 u16* __restrict__ bout1, u16* __restrict__ bout2)  // QKV: kb, vb
{
  constexpr int SMEM_BYTES = (MODE==M_PROJ) ? 64*LNROW*4 : 12288;
  __shared__ __align__(16) char smem[SMEM_BYTES];
  u16* lA = (u16*)smem;            // 64x32 bf16 = 4 KB
  u16* lB = (u16*)(smem + 4096);   // 128x32 bf16 = 8 KB

  const int tid=threadIdx.x;
  const int lane=tid&63, wid=tid>>6;
  const int quad=lane>>4, lrow=lane&15;
  const int m0=blockIdx.x*64, n0=blockIdx.y*128;
  const int wm=(wid&1)*32, wn=(wid>>1)*64;
  f32x4 acc[2][4] = {};

  const int rS=tid>>2, hS=tid&3;   // stage row / 8-elem chunk

  for (int k0=0;k0<K;k0+=32){
    async16(A  + (size_t)(m0+rS)*K    + k0 + hS*8, (char*)lA + tid*16);
    async16(Bt + (size_t)(n0+rS)*K    + k0 + hS*8, (char*)lB + tid*16);
    async16(Bt + (size_t)(n0+64+rS)*K + k0 + hS*8, (char*)lB + (tid+256)*16);
    __syncthreads();
    bf16x8 af[2], bfr[4];
    #pragma unroll
    for (int i=0;i<2;i++) af[i]  = ((const bf16x8*)lA)[(wm+i*16+lrow)*4 + quad];
    #pragma unroll
    for (int j=0;j<4;j++) bfr[j] = ((const bf16x8*)lB)[(wn+j*16+lrow)*4 + quad];
    #pragma unroll
    for (int i=0;i<2;i++)
      #pragma unroll
      for (int j=0;j<4;j++)
        acc[i][j] = __builtin_amdgcn_mfma_f32_16x16x32_bf16(af[i], bfr[j], acc[i][j], 0,0,0);
    __syncthreads();
  }

  const float scale = 0.17677669529663687f;
  float* sLN = (float*)smem;  // PROJ only (safe: loop ended with syncthreads)

  #pragma unroll
  for (int i=0;i<2;i++){
    #pragma unroll
    for (int j=0;j<4;j++){
      #pragma unroll
      for (int r=0;r<4;r++){
        int rl  = wm + i*16 + quad*4 + r;        // row within tile
        int row = m0 + rl;                       // token
        int col = n0 + wn + j*16 + lrow;         // output channel
        float val = acc[i][j][r] + bias[col];
        if (MODE==M_QKV){
          int which = col>>7, ch = col&127;
          u16* dst = (which==0)? bout0 : ((which==1)? bout1 : bout2);
          if (which==0) val *= scale;
          dst[(size_t)row*128 + ch] = f2b(val);
        } else if (MODE==M_PROJ){
          val += aux[(size_t)row*128+col];                   // + x residual
          sLN[rl*LNROW + (col>>5)*LNGRP + (col&31)] = val;
        } else if (MODE==M_FC1){
          float g = 0.5f*val*(1.0f+erff(val*0.70710678118654752f));
          bout0[(size_t)row*512+col]=f2b(g);
        } else {
          val += aux[(size_t)row*128+col];                   // + x1 residual
          fout[(size_t)row*128+col]=val;                     // final fp32 out
        }
      }
    }
  }

  if (MODE==M_PROJ){
    __syncthreads();
    int r2 = tid>>2, q = tid&3;
    const float* base = sLN + r2*LNROW + q*LNGRP;
    float v[32]; float s=0.f, sq=0.f;
    #pragma unroll
    for (int c4=0;c4<8;c4++){
      float4 t = ((const float4*)base)[c4];
      v[c4*4]=t.x; v[c4*4+1]=t.y; v[c4*4+2]=t.z; v[c4*4+3]=t.w;
      s += t.x+t.y+t.z+t.w;
      sq += t.x*t.x+t.y*t.y+t.z*t.z+t.w*t.w;
    }
    s  += __shfl_xor(s,1);  s  += __shfl_xor(s,2);
    sq += __shfl_xor(sq,1); sq += __shfl_xor(sq,2);
    float mean = s*0.0078125f;
    float rr = rsqrtf(sq*0.0078125f - mean*mean + 1e-5f);
    int row = m0 + r2;
    float* x1o = fout + (size_t)row*128 + q*32;
    u16*  xno = bout0 + (size_t)row*128 + q*32;
    #pragma unroll
    for (int c4=0;c4<8;c4++){
      float4 t; t.x=v[c4*4]; t.y=v[c4*4+1]; t.z=v[c4*4+2]; t.w=v[c4*4+3];
      ((float4*)x1o)[c4] = t;
      int col = q*32 + c4*4;
      ushort4 st;
      st.x = f2b((t.x-mean)*rr*lnw[col]   + lnb[col]);
      st.y = f2b((t.y-mean)*rr*lnw[col+1] + lnb[col+1]);
      st.z = f2b((t.z-mean)*rr*lnw[col+2] + lnb[col+2]);
      st.w = f2b((t.w-mean)*rr*lnw[col+3] + lnb[col+3]);
      ((ushort4*)xno)[c4] = st;
    }
  }
}

// ---------- neighborhood attention: 4 threads per (pixel, head), 8 ch each ----------
__global__ __launch_bounds__(256)
void attn_kernel(const u16* __restrict__ qb, const u16* __restrict__ kb,
                 const u16* __restrict__ vb, const float* __restrict__ rpb,
                 u16* __restrict__ aout)
{
  __shared__ float srpb[196];
  int tid = threadIdx.x;
  if (tid < 196) srpb[tid] = rpb[tid];
  __syncthreads();

  int g = blockIdx.x*256 + tid;
  int q4 = g&3, h = (g>>2)&3, t = g>>4;
  int b = t/3136, r0 = t - b*3136, y = r0/56, x0 = r0 - y*56;
  int coff = h*32 + q4*8;

  float qv[8];
  { u16x8 qq = *(const u16x8*)(qb + (size_t)t*128 + coff);
    #pragma unroll
    for (int i=0;i<8;i++) qv[i]=b2f(qq[i]); }

  float sc[49];
  #pragma unroll
  for (int ky=0;ky<7;ky++){
    int gy = y+ky-3; bool rok = (gy>=0)&&(gy<56);
    #pragma unroll
    for (int kx=0;kx<7;kx++){
      int gx = x0+kx-3; int n = ky*7+kx;
      float s = 0.f;
      if (rok && gx>=0 && gx<56){
        int nt = t + (ky-3)*56 + (kx-3);
        u16x8 kk = *(const u16x8*)(kb + (size_t)nt*128 + coff);
        #pragma unroll
        for (int i=0;i<8;i++) s += qv[i]*b2f(kk[i]);
      }
      s += __shfl_xor(s,1); s += __shfl_xor(s,2);   // full 32-ch dot in all 4 lanes
      sc[n] = s + srpb[h*49+n];                     // OOB: 0 + rpb (matches ref)
    }
  }
  float m=-1e30f;
  #pragma unroll
  for (int n=0;n<49;n++) m = fmaxf(m, sc[n]);
  float l=0.f;
  #pragma unroll
  for (int n=0;n<49;n++){ sc[n]=__expf(sc[n]-m); l+=sc[n]; }
  float inv = 1.f/l;

  float o[8]={};
  #pragma unroll
  for (int ky=0;ky<7;ky++){
    int gy = y+ky-3; bool rok = (gy>=0)&&(gy<56);
    #pragma unroll
    for (int kx=0;kx<7;kx++){
      int gx = x0+kx-3; int n = ky*7+kx;
      if (rok && gx>=0 && gx<56){
        int nt = t + (ky-3)*56 + (kx-3);
        u16x8 vv = *(const u16x8*)(vb + (size_t)nt*128 + coff);
        float p = sc[n];
        #pragma unroll
        for (int i=0;i<8;i++) o[i] += p*b2f(vv[i]);
      }
    }
  }
  u16x8 ov;
  #pragma unroll
  for (int i=0;i<8;i++) ov[i] = f2b(o[i]*inv);
  *(u16x8*)(aout + (size_t)t*128 + coff) = ov;
}

extern "C" void kernel_launch(void* const* d_in, const int* in_sizes, int n_in,
                              void* d_out, int out_size, void* d_ws, size_t ws_size,
                              hipStream_t stream)
{
  const float* x     =(const float*)d_in[0];
  const float* ln1w  =(const float*)d_in[1];
  const float* ln1b  =(const float*)d_in[2];
  const float* wqkv  =(const float*)d_in[3];
  const float* bqkv  =(const float*)d_in[4];
  const float* rpb   =(const float*)d_in[5];
  const float* wproj =(const float*)d_in[6];
  const float* bproj =(const float*)d_in[7];
  const float* ln2w  =(const float*)d_in[8];
  const float* ln2b  =(const float*)d_in[9];
  const float* wfc1  =(const float*)d_in[10];
  const float* bfc1  =(const float*)d_in[11];
  const float* wfc2  =(const float*)d_in[12];
  const float* bfc2  =(const float*)d_in[13];

  char* ws=(char*)d_ws;
  size_t o=0;
  u16* tqkv =(u16*)(ws+o); o+=98304;
  u16* tproj=(u16*)(ws+o); o+=32768;
  u16* tfc1 =(u16*)(ws+o); o+=131072;
  u16* tfc2 =(u16*)(ws+o); o+=131072;
  u16* xn   =(u16*)(ws+o); o+=3211264;   // LN1 out bf16 [tok][128]
  u16* aout =(u16*)(ws+o); o+=3211264;   // attn out bf16 [tok][128]
  u16* xn2  =(u16*)(ws+o); o+=3211264;   // LN2 out bf16 [tok][128]
  u16* qb   =(u16*)(ws+o); o+=3211264;   // q scaled bf16 [tok][128]
  u16* kb   =(u16*)(ws+o); o+=3211264;
  u16* vb   =(u16*)(ws+o); o+=3211264;
  u16* hbuf =(u16*)(ws+o); o+=12845056;  // gelu(fc1) bf16 [tok][512]
  float* x1 =(float*)(ws+o); o+=6422528; // x + proj fp32 [tok][128]

  prep_kernel<<<768,256,0,stream>>>(wqkv,wproj,wfc1,wfc2,tqkv,tproj,tfc1,tfc2);
  ln_kernel<<<3136,256,0,stream>>>(x,ln1w,ln1b,xn);
  gemm_kernel<M_QKV><<<dim3(196,3),256,0,stream>>>(xn,tqkv,bqkv,128,
      nullptr,nullptr,nullptr,nullptr, qb,kb,vb);
  attn_kernel<<<784,256,0,stream>>>(qb,kb,vb,rpb,aout);
  gemm_kernel<M_PROJ><<<dim3(196,1),256,0,stream>>>(aout,tproj,bproj,128,
      x, ln2w,ln2b, x1, xn2,nullptr,nullptr);
  gemm_kernel<M_FC1><<<dim3(196,4),256,0,stream>>>(xn2,tfc1,bfc1,128,
      nullptr,nullptr,nullptr,nullptr, hbuf,nullptr,nullptr);
  gemm_kernel<M_FC2><<<dim3(196,1),256,0,stream>>>(hbuf,tfc2,bfc2,512,
      x1,nullptr,nullptr, (float*)d_out, nullptr,nullptr,nullptr);
}

// Round 4
// 157.497 us; speedup vs baseline: 1.4353x; 1.2173x over previous
//
#include <hip/hip_runtime.h>

#define TOKS 12544

using bf16x8 = __attribute__((ext_vector_type(8))) short;
using f32x4  = __attribute__((ext_vector_type(4))) float;
typedef unsigned short u16;
typedef __attribute__((ext_vector_type(8))) unsigned short u16x8;

__device__ __forceinline__ u16 f2b(float f){
  unsigned int i=__float_as_uint(f);
  return (u16)((i + 0x7FFFu + ((i>>16)&1u))>>16);
}
__device__ __forceinline__ float b2f(u16 u){
  union{unsigned int i; float f;}v; v.i=((unsigned int)u)<<16; return v.f;
}
__device__ __forceinline__ void async16(const void* g, void* l){
  __builtin_amdgcn_global_load_lds((__attribute__((address_space(1))) void*)(g),
                                   (__attribute__((address_space(3))) void*)(l), 16, 0, 0);
}

// ---------- prep: fp32 weights -> bf16, transposed to [N][K] ----------
__global__ void prep_kernel(const float* __restrict__ wqkv, const float* __restrict__ wproj,
                            const float* __restrict__ wfc1, const float* __restrict__ wfc2,
                            u16* __restrict__ tqkv, u16* __restrict__ tproj,
                            u16* __restrict__ tfc1, u16* __restrict__ tfc2)
{
  int idx = blockIdx.x*256 + threadIdx.x;
  if (idx < 49152){ int n=idx>>7, k=idx&127; tqkv[idx]=f2b(wqkv[k*384+n]); }
  else if (idx < 65536){ int t=idx-49152; int n=t>>7, k=t&127; tproj[t]=f2b(wproj[k*128+n]); }
  else if (idx < 131072){ int t=idx-65536; int n=t>>7, k=t&127; tfc1[t]=f2b(wfc1[k*512+n]); }
  else if (idx < 196608){ int t=idx-131072; int n=t>>9, k=t&511; tfc2[t]=f2b(wfc2[k*128+n]); }
}

// ---------- layernorm (LN1): wave per token, fp32 in -> bf16 out ----------
__global__ __launch_bounds__(256)
void ln_kernel(const float* __restrict__ xin, const float* __restrict__ w,
               const float* __restrict__ bia, u16* __restrict__ out)
{
  int lane = threadIdx.x & 63;
  int token = blockIdx.x*4 + (threadIdx.x>>6);
  float2 t = ((const float2*)xin)[token*64 + lane];
  float x0=t.x, x1=t.y;
  float s=x0+x1, q=x0*x0+x1*x1;
  #pragma unroll
  for (int off=32; off; off>>=1){ s+=__shfl_xor(s,off); q+=__shfl_xor(q,off); }
  float m = s*0.0078125f;
  float r = rsqrtf(q*0.0078125f - m*m + 1e-5f);
  int c = lane*2;
  ushort2 o;
  o.x = f2b((x0-m)*r*w[c]   + bia[c]);
  o.y = f2b((x1-m)*r*w[c+1] + bia[c+1]);
  ((ushort2*)out)[token*64+lane]=o;
}

// ---------- MFMA GEMM: 64x128 tile; C = A[M,K]*Bt[N,K]^T + bias; fused epilogues ----------
#define M_QKV 0
#define M_PROJ 1
#define M_FC1 2
#define M_FC2 3

// PROJ LN scratch layout: dword idx = row*148 + (col>>5)*36 + (col&31)
#define LNROW 148
#define LNGRP 36

template<int MODE>
__global__ __launch_bounds__(256)
void gemm_kernel(const u16* __restrict__ A, const u16* __restrict__ Bt,
                 const float* __restrict__ bias, int K,
                 const float* __restrict__ aux,     // PROJ: x (fp32); FC2: x1 (fp32)
                 const float* __restrict__ lnw, const float* __restrict__ lnb,
                 float* __restrict__ fout,          // PROJ: x1; FC2: d_out
                 u16* __restrict__ bout0,           // QKV: qb; PROJ: xn2; FC1: hbuf
                 u16* __restrict__ bout1, u16* __restrict__ bout2)  // QKV: kb, vb
{
  constexpr int SMEM_BYTES = (MODE==M_PROJ) ? 64*LNROW*4 : 12288;
  __shared__ __align__(16) char smem[SMEM_BYTES];
  u16* lA = (u16*)smem;            // 64x32 bf16 = 4 KB
  u16* lB = (u16*)(smem + 4096);   // 128x32 bf16 = 8 KB

  const int tid=threadIdx.x;
  const int lane=tid&63, wid=tid>>6;
  const int quad=lane>>4, lrow=lane&15;
  const int m0=blockIdx.x*64, n0=blockIdx.y*128;
  const int wm=(wid&1)*32, wn=(wid>>1)*64;
  f32x4 acc[2][4] = {};

  const int rS=tid>>2, hS=tid&3;   // stage row / 8-elem chunk

  for (int k0=0;k0<K;k0+=32){
    async16(A  + (size_t)(m0+rS)*K    + k0 + hS*8, (char*)lA + tid*16);
    async16(Bt + (size_t)(n0+rS)*K    + k0 + hS*8, (char*)lB + tid*16);
    async16(Bt + (size_t)(n0+64+rS)*K + k0 + hS*8, (char*)lB + (tid+256)*16);
    __syncthreads();
    bf16x8 af[2], bfr[4];
    #pragma unroll
    for (int i=0;i<2;i++) af[i]  = ((const bf16x8*)lA)[(wm+i*16+lrow)*4 + quad];
    #pragma unroll
    for (int j=0;j<4;j++) bfr[j] = ((const bf16x8*)lB)[(wn+j*16+lrow)*4 + quad];
    #pragma unroll
    for (int i=0;i<2;i++)
      #pragma unroll
      for (int j=0;j<4;j++)
        acc[i][j] = __builtin_amdgcn_mfma_f32_16x16x32_bf16(af[i], bfr[j], acc[i][j], 0,0,0);
    __syncthreads();
  }

  const float scale = 0.17677669529663687f;
  float* sLN = (float*)smem;  // PROJ only (safe: loop ended with syncthreads)

  #pragma unroll
  for (int i=0;i<2;i++){
    #pragma unroll
    for (int j=0;j<4;j++){
      #pragma unroll
      for (int r=0;r<4;r++){
        int rl  = wm + i*16 + quad*4 + r;        // row within tile
        int row = m0 + rl;                       // token
        int col = n0 + wn + j*16 + lrow;         // output channel
        float val = acc[i][j][r] + bias[col];
        if (MODE==M_QKV){
          int which = col>>7, ch = col&127;
          u16* dst = (which==0)? bout0 : ((which==1)? bout1 : bout2);
          if (which==0) val *= scale;
          dst[(size_t)row*128 + ch] = f2b(val);
        } else if (MODE==M_PROJ){
          val += aux[(size_t)row*128+col];                   // + x residual
          sLN[rl*LNROW + (col>>5)*LNGRP + (col&31)] = val;
        } else if (MODE==M_FC1){
          float g = 0.5f*val*(1.0f+erff(val*0.70710678118654752f));
          bout0[(size_t)row*512+col]=f2b(g);
        } else {
          val += aux[(size_t)row*128+col];                   // + x1 residual
          fout[(size_t)row*128+col]=val;                     // final fp32 out
        }
      }
    }
  }

  if (MODE==M_PROJ){
    __syncthreads();
    int r2 = tid>>2, q = tid&3;
    const float* base = sLN + r2*LNROW + q*LNGRP;
    float v[32]; float s=0.f, sq=0.f;
    #pragma unroll
    for (int c4=0;c4<8;c4++){
      float4 t = ((const float4*)base)[c4];
      v[c4*4]=t.x; v[c4*4+1]=t.y; v[c4*4+2]=t.z; v[c4*4+3]=t.w;
      s += t.x+t.y+t.z+t.w;
      sq += t.x*t.x+t.y*t.y+t.z*t.z+t.w*t.w;
    }
    s  += __shfl_xor(s,1);  s  += __shfl_xor(s,2);
    sq += __shfl_xor(sq,1); sq += __shfl_xor(sq,2);
    float mean = s*0.0078125f;
    float rr = rsqrtf(sq*0.0078125f - mean*mean + 1e-5f);
    int row = m0 + r2;
    float* x1o = fout + (size_t)row*128 + q*32;
    u16*  xno = bout0 + (size_t)row*128 + q*32;
    #pragma unroll
    for (int c4=0;c4<8;c4++){
      float4 t; t.x=v[c4*4]; t.y=v[c4*4+1]; t.z=v[c4*4+2]; t.w=v[c4*4+3];
      ((float4*)x1o)[c4] = t;
      int col = q*32 + c4*4;
      ushort4 st;
      st.x = f2b((t.x-mean)*rr*lnw[col]   + lnb[col]);
      st.y = f2b((t.y-mean)*rr*lnw[col+1] + lnb[col+1]);
      st.z = f2b((t.z-mean)*rr*lnw[col+2] + lnb[col+2]);
      st.w = f2b((t.w-mean)*rr*lnw[col+3] + lnb[col+3]);
      ((ushort4*)xno)[c4] = st;
    }
  }
}

// ---------- neighborhood attention: LDS-tiled ----------
// Block = 8x8 pixel tile x (batch, head). Stage 14x14 halo of K,V (bf16, 32ch)
// into LDS, then thread=(pixel, channel-quarter) computes from LDS only.
__global__ __launch_bounds__(256)
void attn_kernel(const u16* __restrict__ qb, const u16* __restrict__ kb,
                 const u16* __restrict__ vb, const float* __restrict__ rpb,
                 u16* __restrict__ aout)
{
  __shared__ __align__(16) u16 kt[196*32];
  __shared__ __align__(16) u16 vt[196*32];

  const int tid = threadIdx.x;
  const int tile = blockIdx.x;            // 0..48 : 7x7 tiles of 8x8
  const int bh = blockIdx.y;              // b*4 + h
  const int b = bh>>2, h = bh&3;
  const int ty = (tile/7)*8, tx = (tile%7)*8;

  // ---- stage K,V halo: 196 pos x 4 chunks of 16B each ----
  #pragma unroll
  for (int k=0;k<4;k++){
    int i = tid + k*256;
    if (i < 784){
      int pos = i>>2, c = i&3;
      int ly = pos/14, lx = pos-ly*14;
      int gy = ty + ly - 3, gx = tx + lx - 3;
      float4 kv = {0,0,0,0}, vv = {0,0,0,0};
      if (gy>=0 && gy<56 && gx>=0 && gx<56){
        size_t base = ((size_t)(b*3136 + gy*56 + gx)*128 + h*32 + c*8);
        kv = *(const float4*)(kb + base);
        vv = *(const float4*)(vb + base);
      }
      ((float4*)kt)[i] = kv;
      ((float4*)vt)[i] = vv;
    }
  }
  __syncthreads();

  const int px = tid>>2, q = tid&3;       // pixel 0..63, channel quarter
  const int ly = px>>3, lx = px&7;
  const int tok = b*3136 + (ty+ly)*56 + (tx+lx);
  const int nbase = (ly*14 + lx)*32 + q*8;   // u16 offset of neighbor (0,0)

  float qv[8];
  { u16x8 qq = *(const u16x8*)(qb + (size_t)tok*128 + h*32 + q*8);
    #pragma unroll
    for (int i=0;i<8;i++) qv[i]=b2f(qq[i]); }

  float sc[49];
  #pragma unroll
  for (int ky=0;ky<7;ky++){
    #pragma unroll
    for (int kx=0;kx<7;kx++){
      int n = ky*7+kx;
      u16x8 kk = *(const u16x8*)(kt + nbase + (ky*14+kx)*32);
      float s = 0.f;
      #pragma unroll
      for (int i=0;i<8;i++) s += qv[i]*b2f(kk[i]);
      s += __shfl_xor(s,1); s += __shfl_xor(s,2);   // reduce over 4 quarters
      sc[n] = s + rpb[h*49+n];                      // scalar (uniform) load
    }
  }
  float m=-1e30f;
  #pragma unroll
  for (int n=0;n<49;n++) m = fmaxf(m, sc[n]);
  float l=0.f;
  #pragma unroll
  for (int n=0;n<49;n++){ sc[n]=__expf(sc[n]-m); l+=sc[n]; }
  float inv = 1.f/l;

  float o[8]={};
  #pragma unroll
  for (int ky=0;ky<7;ky++){
    #pragma unroll
    for (int kx=0;kx<7;kx++){
      int n = ky*7+kx;
      u16x8 vv = *(const u16x8*)(vt + nbase + (ky*14+kx)*32);
      float p = sc[n];
      #pragma unroll
      for (int i=0;i<8;i++) o[i] += p*b2f(vv[i]);
    }
  }
  u16x8 ov;
  #pragma unroll
  for (int i=0;i<8;i++) ov[i] = f2b(o[i]*inv);
  *(u16x8*)(aout + (size_t)tok*128 + h*32 + q*8) = ov;
}

extern "C" void kernel_launch(void* const* d_in, const int* in_sizes, int n_in,
                              void* d_out, int out_size, void* d_ws, size_t ws_size,
                              hipStream_t stream)
{
  const float* x     =(const float*)d_in[0];
  const float* ln1w  =(const float*)d_in[1];
  const float* ln1b  =(const float*)d_in[2];
  const float* wqkv  =(const float*)d_in[3];
  const float* bqkv  =(const float*)d_in[4];
  const float* rpb   =(const float*)d_in[5];
  const float* wproj =(const float*)d_in[6];
  const float* bproj =(const float*)d_in[7];
  const float* ln2w  =(const float*)d_in[8];
  const float* ln2b  =(const float*)d_in[9];
  const float* wfc1  =(const float*)d_in[10];
  const float* bfc1  =(const float*)d_in[11];
  const float* wfc2  =(const float*)d_in[12];
  const float* bfc2  =(const float*)d_in[13];

  char* ws=(char*)d_ws;
  size_t o=0;
  u16* tqkv =(u16*)(ws+o); o+=98304;
  u16* tproj=(u16*)(ws+o); o+=32768;
  u16* tfc1 =(u16*)(ws+o); o+=131072;
  u16* tfc2 =(u16*)(ws+o); o+=131072;
  u16* xn   =(u16*)(ws+o); o+=3211264;   // LN1 out bf16 [tok][128]
  u16* aout =(u16*)(ws+o); o+=3211264;   // attn out bf16 [tok][128]
  u16* xn2  =(u16*)(ws+o); o+=3211264;   // LN2 out bf16 [tok][128]
  u16* qb   =(u16*)(ws+o); o+=3211264;   // q scaled bf16 [tok][128]
  u16* kb   =(u16*)(ws+o); o+=3211264;
  u16* vb   =(u16*)(ws+o); o+=3211264;
  u16* hbuf =(u16*)(ws+o); o+=12845056;  // gelu(fc1) bf16 [tok][512]
  float* x1 =(float*)(ws+o); o+=6422528; // x + proj fp32 [tok][128]

  prep_kernel<<<768,256,0,stream>>>(wqkv,wproj,wfc1,wfc2,tqkv,tproj,tfc1,tfc2);
  ln_kernel<<<3136,256,0,stream>>>(x,ln1w,ln1b,xn);
  gemm_kernel<M_QKV><<<dim3(196,3),256,0,stream>>>(xn,tqkv,bqkv,128,
      nullptr,nullptr,nullptr,nullptr, qb,kb,vb);
  attn_kernel<<<dim3(49,16),256,0,stream>>>(qb,kb,vb,rpb,aout);
  gemm_kernel<M_PROJ><<<dim3(196,1),256,0,stream>>>(aout,tproj,bproj,128,
      x, ln2w,ln2b, x1, xn2,nullptr,nullptr);
  gemm_kernel<M_FC1><<<dim3(196,4),256,0,stream>>>(xn2,tfc1,bfc1,128,
      nullptr,nullptr,nullptr,nullptr, hbuf,nullptr,nullptr);
  gemm_kernel<M_FC2><<<dim3(196,1),256,0,stream>>>(hbuf,tfc2,bfc2,512,
      x1,nullptr,nullptr, (float*)d_out, nullptr,nullptr,nullptr);
}